// Round 8
// baseline (238.347 us; speedup 1.0000x reference)
//
#include <hip/hip_runtime.h>

// IDWT 2D (Haar 2x2 filter bank), R12 (= R11 resubmitted byte-identical;
// round 7 was an infra failure with no data).
//
// Ledger through R10: six structural variants (NT 1px / dword 4px / dwordx4 /
// SGPR-pipelined 16px / +NT / LDS single-stream-per-wave) ALL land 69-83 us.
// Traffic compulsory-minimal (FETCH 64 MiB, WRITE 128 MiB exact), 0 bank
// conflicts, VALUBusy ~3%. We sustain 2.5 TB/s HBM-side; the harness fill
// does 6.7 TB/s AT 9% OCCUPANCY on the same machine state.
//
// Last un-isolated axis: CONCURRENCY / per-stream burst length. Theory: with
// 11-32 waves/CU, each HBM channel sees many interleaved short read streams
// -> DRAM row-buffer thrash -> ~40% of ceiling (writes escape via controller
// merging, which is why the low-occupancy fill flies). R11/R12 mimics the
// fill:
//   - 512 blocks (2/CU, 8 waves/CU, 25% occupancy), block owns 16384
//     CONTIGUOUS pixels = 8 groups of 2048.
//   - Wave k reads ONLY subband k: one sequential 64 KB stream per wave,
//     8 KB burst per group (8x dwordx4, 1 KiB contiguous per instr).
//   - Double-buffered LDS (2x32 KB): reg-stage group g+1 issued right after
//     the barrier, landing during group g's compute+store.
//   - Compute: 4x ds_read_b32 + FMA from SGPR filters; stores 1 KiB-
//     contiguous dwordx4 (out = float4[pixel]).
//
// Pre-registered: kernel -> 45-60 us = theory confirmed; 75-85 us = all axes
// exonerated -> declare ROOFLINE next round; >=90 us = occupancy helps, push
// the other way.

typedef float floatx4 __attribute__((ext_vector_type(4)));

constexpr long SUB_STRIDE = 1L << 20;    // C*H*W floats (4 MiB per subband)
constexpr long P_TOTAL    = 8L << 20;    // 8,388,608 pixels
constexpr int  G          = 2048;        // pixels per group
constexpr int  BLOCKS     = 512;         // 2 blocks/CU
constexpr int  GPB        = (int)(P_TOTAL / ((long)BLOCKS * G));  // 8 groups

__global__ __launch_bounds__(256) void idwt2d_kernel(
    const float* __restrict__ x,
    const float* __restrict__ f,
    float* __restrict__ out)
{
    __shared__ float lds[2][4][G];       // 64 KB -> 2 blocks/CU fit (128/160)

    const int tid  = threadIdx.x;
    const int lane = tid & 63;
    const int wv   = tid >> 6;

    // Filters into SGPRs (wave-uniform).
    float fs[16];
#pragma unroll
    for (int i = 0; i < 16; ++i)
        fs[i] = __uint_as_float(
            (unsigned)__builtin_amdgcn_readfirstlane((int)__float_as_uint(f[i])));

    // Block owns pixels [PB0, PB0+16384); 16384 | 2^20 -> n block-uniform.
    const long PB0 = (long)blockIdx.x * (GPB * G);
    const long n   = PB0 >> 20;

    // Wave-private sequential read stream: subband wv only.
    const floatx4* src = (const floatx4*)(x + PB0 + (3 * n + wv) * SUB_STRIDE);
    floatx4* o4 = (floatx4*)out + PB0;   // out float offset = 4*pixel

    floatx4 cur[8], nxt[8];
#pragma unroll
    for (int i = 0; i < 8; ++i)          // prologue: group 0 burst (8 KB/wave)
        cur[i] = src[i * 64 + lane];

#pragma unroll
    for (int g = 0; g < GPB; ++g) {
        // Stage group g into LDS buffer g&1 (waits cur's loads; covered by
        // previous iteration's compute).
        floatx4* dst = (floatx4*)lds[g & 1][wv];
#pragma unroll
        for (int i = 0; i < 8; ++i)
            dst[i * 64 + lane] = cur[i];

        __syncthreads();

        // Issue group g+1's burst AFTER the barrier; completes under compute.
        if (g + 1 < GPB) {
            const floatx4* s2 = src + (long)(g + 1) * (G / 4);
#pragma unroll
            for (int i = 0; i < 8; ++i)
                nxt[i] = s2[i * 64 + lane];
        }

        // Compute + store group g (8 pixels/thread).
#pragma unroll
        for (int j = 0; j < G / 256; ++j) {
            const int p = tid + j * 256;
            const float v0 = lds[g & 1][0][p];
            const float v1 = lds[g & 1][1][p];
            const float v2 = lds[g & 1][2][p];
            const float v3 = lds[g & 1][3][p];
            floatx4 r;
#pragma unroll
            for (int ab = 0; ab < 4; ++ab)
                r[ab] = fs[ab] * v0 + fs[4 + ab] * v1
                      + fs[8 + ab] * v2 + fs[12 + ab] * v3;
            o4[(long)g * G + p] = r;
        }

        // Hand off (full unroll -> pure register renaming). Cross-iteration
        // LDS reuse hazard (buffer g&1 rewritten at g+2) is fenced by the
        // g+1 iteration's __syncthreads.
#pragma unroll
        for (int i = 0; i < 8; ++i)
            cur[i] = nxt[i];
    }
}

extern "C" void kernel_launch(void* const* d_in, const int* in_sizes, int n_in,
                              void* d_out, int out_size, void* d_ws, size_t ws_size,
                              hipStream_t stream)
{
    const float* x   = (const float*)d_in[0];
    const float* flt = (const float*)d_in[1];
    float* out       = (float*)d_out;

    idwt2d_kernel<<<BLOCKS, 256, 0, stream>>>(x, flt, out);
}